// Round 3
// baseline (20659.477 us; speedup 1.0000x reference)
//
#include <hip/hip_runtime.h>
#include <hip/hip_bf16.h>

#define S_LEN 8192
#define LC 16
#define CE 64
#define CH 64
#define WE 128
#define NTAGS 50

using bf16 = __hip_bfloat16;
typedef unsigned int u32;
typedef unsigned long long u64;

__device__ __forceinline__ float bfbits2f(unsigned short u) {
    union { unsigned int i; float f; } v; v.i = ((unsigned int)u) << 16; return v.f;
}
__device__ __forceinline__ float sigm(float x) {
    return __builtin_amdgcn_rcpf(1.0f + __expf(-x));
}
__device__ __forceinline__ float tanh_fast(float x) {
    return 1.0f - 2.0f * __builtin_amdgcn_rcpf(__expf(2.0f * x) + 1.0f);
}

// dtype-generic accessors ----------------------------------------------------
template <bool BF>
__device__ __forceinline__ float ld1(const void* p, size_t i) {
    if constexpr (BF) return bfbits2f(((const unsigned short*)p)[i]);
    else              return ((const float*)p)[i];
}
template <bool BF>
__device__ __forceinline__ float4 ld4(const void* p, size_t i) {  // elems i..i+3
    if constexpr (BF) {
        const ushort4 s = *reinterpret_cast<const ushort4*>((const unsigned short*)p + i);
        return make_float4(bfbits2f(s.x), bfbits2f(s.y), bfbits2f(s.z), bfbits2f(s.w));
    } else {
        return *reinterpret_cast<const float4*>((const float*)p + i);
    }
}
template <bool BF>
__device__ __forceinline__ void st1(void* p, size_t i, float v) {
    if constexpr (BF) ((bf16*)p)[i] = __float2bfloat16(v);
    else              ((float*)p)[i] = v;
}

// ---------------------------------------------------------------------------
// Detector: classify float-tensor dtype from char_emb's first 256 ushorts.
// bf16 data: every ushort has exponent field ~[100,133] (values ~0.1-scale).
// f32 data: only the high ushort of each float does (~56% overall).
// ---------------------------------------------------------------------------
__global__ void kdetect(const void* emb, u32* flag) {
    const int j = threadIdx.x;           // 64 lanes
    int s = 0;
    #pragma unroll
    for (int k = 0; k < 4; ++k) {
        const unsigned short u = ((const unsigned short*)emb)[j * 4 + k];
        const int e = (u >> 7) & 0xFF;
        s += (e >= 100 && e <= 133) ? 1 : 0;
    }
    #pragma unroll
    for (int off = 32; off >= 1; off >>= 1) s += __shfl_xor(s, off, 64);
    if (j == 0) *flag = (s >= 200) ? 1u : 0u;
}

// ---------------------------------------------------------------------------
// Kernel A: char LSTM. 8 words/block, 256 threads (thread j = gate row j).
// ---------------------------------------------------------------------------
template <bool BF>
__global__ __launch_bounds__(256, 2) void kchar(
        const u32* __restrict__ dtf,
        const int* __restrict__ char_idxs, const int* __restrict__ char_lens,
        const void* __restrict__ char_emb,
        const void* __restrict__ Wih, const void* __restrict__ Whh,
        const void* __restrict__ bih, const void* __restrict__ bhh,
        float* __restrict__ cfeat) {
    if ((*dtf != 0u) != BF) return;
    const int j = threadIdx.x;
    const int w0 = blockIdx.x * 8;

    __shared__ __align__(16) float emb_lds[128 * CE];     // 32 KB
    __shared__ __align__(16) float gates_lds[8 * 256];    // 8 KB
    __shared__ __align__(16) float h_lds[8 * CH];
    __shared__ __align__(16) float c_lds[8 * CH];
    __shared__ int cidx_lds[8 * LC];
    __shared__ int len_lds[8];

    {
        float4* emb4 = reinterpret_cast<float4*>(emb_lds);
        #pragma unroll
        for (int i = 0; i < 8; ++i) {
            const int c = i * 256 + j;
            emb4[c] = ld4<BF>(char_emb, (size_t)c * 4);
        }
    }
    if (j < 128) cidx_lds[j] = char_idxs[w0 * LC + j];
    if (j < 8)   len_lds[j]  = char_lens[w0 + j];
    h_lds[j] = 0.f; h_lds[j + 256] = 0.f;
    c_lds[j] = 0.f; c_lds[j + 256] = 0.f;

    float4 wih4[16], whh4[16];
    #pragma unroll
    for (int kc = 0; kc < 16; ++kc) {
        wih4[kc] = ld4<BF>(Wih, (size_t)j * CE + kc * 4);
        whh4[kc] = ld4<BF>(Whh, (size_t)j * CH + kc * 4);
    }
    const float bias = ld1<BF>(bih, j) + ld1<BF>(bhh, j);
    __syncthreads();

    for (int t = 0; t < LC; ++t) {
        for (int w = 0; w < 8; ++w) {
            const int ci = cidx_lds[w * LC + t];
            const float4* x4  = reinterpret_cast<const float4*>(emb_lds + ci * CE);
            const float4* hh4 = reinterpret_cast<const float4*>(h_lds + w * CH);
            float a0 = 0.f, a1 = 0.f, a2 = 0.f, a3 = 0.f;
            #pragma unroll
            for (int kc = 0; kc < 16; ++kc) {
                const float4 xv = x4[kc]; const float4 hv = hh4[kc];
                const float4 wi = wih4[kc]; const float4 wh = whh4[kc];
                a0 = fmaf(wi.x, xv.x, a0); a1 = fmaf(wi.y, xv.y, a1);
                a2 = fmaf(wi.z, xv.z, a2); a3 = fmaf(wi.w, xv.w, a3);
                a0 = fmaf(wh.x, hv.x, a0); a1 = fmaf(wh.y, hv.y, a1);
                a2 = fmaf(wh.z, hv.z, a2); a3 = fmaf(wh.w, hv.w, a3);
            }
            gates_lds[w * 256 + j] = bias + ((a0 + a1) + (a2 + a3));
        }
        __syncthreads();
        #pragma unroll
        for (int rep = 0; rep < 2; ++rep) {
            const int p = j + rep * 256;       // p = w*64 + u
            const int w = p >> 6, u = p & 63;
            const float ig = gates_lds[w * 256 + u];
            const float fg = gates_lds[w * 256 + 64 + u];
            const float gg = gates_lds[w * 256 + 128 + u];
            const float og = gates_lds[w * 256 + 192 + u];
            const float cn = sigm(fg) * c_lds[p] + sigm(ig) * tanh_fast(gg);
            const float hn = sigm(og) * tanh_fast(cn);
            c_lds[p] = cn; h_lds[p] = hn;
            if (t == len_lds[w] - 1)
                cfeat[(size_t)(w0 + w) * CH + u] = hn;
        }
        __syncthreads();
    }
}

// ---------------------------------------------------------------------------
// Kernel B: Gx ring chunk. 16 words/block.
// ---------------------------------------------------------------------------
template <bool BF>
__global__ __launch_bounds__(256) void kgx(
        const u32* __restrict__ dtf,
        int t0, const int* __restrict__ word_idxs, const float* __restrict__ cfeat,
        const void* __restrict__ wemb, const void* __restrict__ Wih,
        const void* __restrict__ bih, const void* __restrict__ bhh,
        float* __restrict__ Gxr) {
    if ((*dtf != 0u) != BF) return;
    const int j = threadIdx.x;
    const int wr0 = blockIdx.x * 16;       // ring row base
    const int w0g = t0 + wr0;              // global word base
    __shared__ __align__(16) float wx[16 * 192];
    __shared__ int widx[16];
    if (j < 16) widx[j] = word_idxs[w0g + j];
    __syncthreads();
    {
        const int w = j >> 4, ch = j & 15;
        const size_t eb = (size_t)widx[w] * WE + ch * 8;
        const float4 f0 = ld4<BF>(wemb, eb), f1 = ld4<BF>(wemb, eb + 4);
        float4* dst = reinterpret_cast<float4*>(wx + w * 192 + ch * 8);
        dst[0] = f0; dst[1] = f1;
        const float4 cf = *reinterpret_cast<const float4*>(
            cfeat + (size_t)(w0g + w) * CH + ch * 4);
        *reinterpret_cast<float4*>(wx + w * 192 + WE + ch * 4) = cf;
    }
    __syncthreads();

    for (int g = 0; g < 4; ++g) {
        const int r = g * 256 + j;
        float acc[16];
        #pragma unroll
        for (int w = 0; w < 16; ++w) acc[w] = 0.f;
        #pragma unroll 8
        for (int kc = 0; kc < 48; ++kc) {
            const float4 wv = ld4<BF>(Wih, (size_t)r * 192 + kc * 4);
            #pragma unroll
            for (int w = 0; w < 16; ++w) {
                const float4 xv = *reinterpret_cast<const float4*>(wx + w * 192 + kc * 4);
                acc[w] = fmaf(wv.x, xv.x, acc[w]);
                acc[w] = fmaf(wv.y, xv.y, acc[w]);
                acc[w] = fmaf(wv.z, xv.z, acc[w]);
                acc[w] = fmaf(wv.w, xv.w, acc[w]);
            }
        }
        const float bias = ld1<BF>(bih, r) + ld1<BF>(bhh, r);
        #pragma unroll
        for (int w = 0; w < 16; ++w)
            Gxr[(size_t)(wr0 + w) * 1024 + r] = acc[w] + bias;
    }
}

// ---------------------------------------------------------------------------
// Kernel C: word LSTM steps [t0, t1). 4 blocks x 256 threads; block b owns
// hidden units [64b, 64b+64). Cross-block h exchange via self-validating
// (tag,value) u64 packets; parity-2 slot reuse safe by data dependence.
// ---------------------------------------------------------------------------
template <bool BF>
__global__ __launch_bounds__(256, 1) void kwlstm(
        const u32* __restrict__ dtf,
        int t0, int t1, const void* __restrict__ whh, const float* __restrict__ Gxr,
        float* __restrict__ hallr, u64* hgx2, float* csave) {
    if ((*dtf != 0u) != BF) return;
    const int b = blockIdx.x, j = threadIdx.x;
    const int gsel = j >> 6, u = j & 63;
    const int row = gsel * 256 + b * 64 + u;

    __shared__ __align__(16) float h_cur[256];
    __shared__ __align__(16) float gates[256];

    float4 wv[64];
    #pragma unroll
    for (int kc = 0; kc < 64; ++kc)
        wv[kc] = ld4<BF>(whh, (size_t)row * 256 + kc * 4);
    h_cur[j] = 0.f;
    float c_reg = 0.f;
    if (t0 > 0 && j < 64) c_reg = csave[b * 64 + j];
    __syncthreads();

    for (int t = t0; t < t1; ++t) {
        const float gxv = Gxr[(size_t)(t - t0) * 1024 + row];
        if (t > 0) {
            u64 pk;
            do {
                pk = __hip_atomic_load(&hgx2[(size_t)(t & 1) * 256 + j],
                                       __ATOMIC_RELAXED, __HIP_MEMORY_SCOPE_AGENT);
            } while ((u32)(pk >> 32) != (u32)t);
            h_cur[j] = __uint_as_float((u32)pk);
        }
        __syncthreads();
        float a0 = 0.f, a1 = 0.f, a2 = 0.f, a3 = 0.f;
        const float4* h4 = reinterpret_cast<const float4*>(h_cur);
        #pragma unroll
        for (int kc = 0; kc < 64; ++kc) {
            const float4 hv = h4[kc];
            a0 = fmaf(wv[kc].x, hv.x, a0);
            a1 = fmaf(wv[kc].y, hv.y, a1);
            a2 = fmaf(wv[kc].z, hv.z, a2);
            a3 = fmaf(wv[kc].w, hv.w, a3);
        }
        gates[j] = gxv + ((a0 + a1) + (a2 + a3));
        __syncthreads();
        if (j < 64) {
            const float ig = gates[j], fg = gates[64 + j];
            const float gg = gates[128 + j], og = gates[192 + j];
            const float cn = sigm(fg) * c_reg + sigm(ig) * tanh_fast(gg);
            c_reg = cn;
            const float hn = sigm(og) * tanh_fast(cn);
            hallr[(size_t)(t - t0) * 256 + b * 64 + j] = hn;
            const u64 pk = ((u64)(u32)(t + 1) << 32) | (u64)__float_as_uint(hn);
            __hip_atomic_store(&hgx2[(size_t)((t + 1) & 1) * 256 + b * 64 + j], pk,
                               __ATOMIC_RELAXED, __HIP_MEMORY_SCOPE_AGENT);
        }
        __syncthreads();
    }
    if (j < 64) csave[b * 64 + j] = c_reg;
}

// ---------------------------------------------------------------------------
// Kernel D: logits + log_softmax. One wave per word.
// ---------------------------------------------------------------------------
template <bool BF>
__global__ __launch_bounds__(64) void ktag(
        const u32* __restrict__ dtf,
        int t0, const float* __restrict__ hallr, const void* __restrict__ tagW,
        const void* __restrict__ tagb, void* __restrict__ out) {
    if ((*dtf != 0u) != BF) return;
    const int tr = blockIdx.x, j = threadIdx.x;
    const int t = t0 + tr;
    __shared__ __align__(16) float4 h4[64];
    h4[j] = reinterpret_cast<const float4*>(hallr + (size_t)tr * 256)[j];
    __syncthreads();
    float logit = -1e30f;
    if (j < NTAGS) {
        float a0 = 0.f, a1 = 0.f, a2 = 0.f, a3 = 0.f;
        #pragma unroll
        for (int kc = 0; kc < 64; ++kc) {
            const float4 wvv = ld4<BF>(tagW, (size_t)j * 256 + kc * 4);
            const float4 hv = h4[kc];
            a0 = fmaf(wvv.x, hv.x, a0); a1 = fmaf(wvv.y, hv.y, a1);
            a2 = fmaf(wvv.z, hv.z, a2); a3 = fmaf(wvv.w, hv.w, a3);
        }
        logit = ld1<BF>(tagb, j) + ((a0 + a1) + (a2 + a3));
    }
    float m = logit;
    #pragma unroll
    for (int off = 32; off >= 1; off >>= 1) m = fmaxf(m, __shfl_xor(m, off, 64));
    const float e = (j < NTAGS) ? __expf(logit - m) : 0.f;
    float ssum = e;
    #pragma unroll
    for (int off = 32; off >= 1; off >>= 1) ssum += __shfl_xor(ssum, off, 64);
    if (j < NTAGS)
        st1<BF>(out, (size_t)t * NTAGS + j, logit - m - __logf(ssum));
}

// ---------------------------------------------------------------------------
extern "C" void kernel_launch(void* const* d_in, const int* in_sizes, int n_in,
                              void* d_out, int out_size, void* d_ws, size_t ws_size,
                              hipStream_t stream) {
    const int*  word_idxs = (const int*)d_in[0];
    const int*  char_idxs = (const int*)d_in[1];
    const int*  char_lens = (const int*)d_in[2];
    const void* char_emb  = d_in[3];
    const void* char_Wih  = d_in[4];
    const void* char_Whh  = d_in[5];
    const void* char_bih  = d_in[6];
    const void* char_bhh  = d_in[7];
    const void* word_emb  = d_in[8];
    const void* word_Wih  = d_in[9];
    const void* word_Whh  = d_in[10];
    const void* word_bih  = d_in[11];
    const void* word_bhh  = d_in[12];
    const void* tag_W     = d_in[13];
    const void* tag_b     = d_in[14];

    // ws layout:
    //   [0,64)        dtflag u32
    //   [64,4160)     hgx2 u64[2][256]
    //   [4224,5248)   csave f32[256]
    //   [8192,+2MB)   cfeat f32[8192*64]
    //   [ring0,...)   Gx ring f32[CT*1024] + hall ring f32[CT*256]
    char* ws = (char*)d_ws;
    u32*   dtf   = (u32*)(ws);
    u64*   hgx2  = (u64*)(ws + 64);
    float* csave = (float*)(ws + 4224);
    float* cfeat = (float*)(ws + 8192);
    const size_t ring0 = 8192 + (size_t)S_LEN * CH * 4;

    int NC = 256;
    const int ncs[9] = {1, 2, 4, 8, 16, 32, 64, 128, 256};
    for (int i = 0; i < 9; ++i) {
        const int ct = S_LEN / ncs[i];
        if (ring0 + (size_t)ct * 5120 <= ws_size) { NC = ncs[i]; break; }
    }
    const int CT = S_LEN / NC;
    float* Gxr   = (float*)(ws + ring0);
    float* hallr = (float*)(ws + ring0 + (size_t)CT * 4096);

    hipLaunchKernelGGL(kdetect, dim3(1), dim3(64), 0, stream, char_emb, dtf);
    hipLaunchKernelGGL(kchar<true>,  dim3(S_LEN / 8), dim3(256), 0, stream,
                       dtf, char_idxs, char_lens, char_emb, char_Wih, char_Whh,
                       char_bih, char_bhh, cfeat);
    hipLaunchKernelGGL(kchar<false>, dim3(S_LEN / 8), dim3(256), 0, stream,
                       dtf, char_idxs, char_lens, char_emb, char_Wih, char_Whh,
                       char_bih, char_bhh, cfeat);
    for (int c = 0; c < NC; ++c) {
        const int t0 = c * CT;
        hipLaunchKernelGGL(kgx<true>,  dim3(CT / 16), dim3(256), 0, stream,
                           dtf, t0, word_idxs, cfeat, word_emb, word_Wih,
                           word_bih, word_bhh, Gxr);
        hipLaunchKernelGGL(kgx<false>, dim3(CT / 16), dim3(256), 0, stream,
                           dtf, t0, word_idxs, cfeat, word_emb, word_Wih,
                           word_bih, word_bhh, Gxr);
        hipLaunchKernelGGL(kwlstm<true>,  dim3(4), dim3(256), 0, stream,
                           dtf, t0, t0 + CT, word_Whh, Gxr, hallr, hgx2, csave);
        hipLaunchKernelGGL(kwlstm<false>, dim3(4), dim3(256), 0, stream,
                           dtf, t0, t0 + CT, word_Whh, Gxr, hallr, hgx2, csave);
        hipLaunchKernelGGL(ktag<true>,  dim3(CT), dim3(64), 0, stream,
                           dtf, t0, hallr, tag_W, tag_b, d_out);
        hipLaunchKernelGGL(ktag<false>, dim3(CT), dim3(64), 0, stream,
                           dtf, t0, hallr, tag_W, tag_b, d_out);
    }
}

// Round 4
// 12705.553 us; speedup vs baseline: 1.6260x; 1.6260x over previous
//
#include <hip/hip_runtime.h>
#include <hip/hip_bf16.h>

#define S_LEN 8192
#define LC 16
#define CE 64
#define CH 64
#define WE 128
#define NTAGS 50

using bf16 = __hip_bfloat16;
typedef unsigned int u32;
typedef unsigned long long u64;

__device__ __forceinline__ float bfbits2f(unsigned short u) {
    union { unsigned int i; float f; } v; v.i = ((unsigned int)u) << 16; return v.f;
}
__device__ __forceinline__ float sigm(float x) {
    return __builtin_amdgcn_rcpf(1.0f + __expf(-x));
}
__device__ __forceinline__ float tanh_fast(float x) {
    return 1.0f - 2.0f * __builtin_amdgcn_rcpf(__expf(2.0f * x) + 1.0f);
}

// dtype-generic accessors ----------------------------------------------------
template <bool BF>
__device__ __forceinline__ float ld1(const void* p, size_t i) {
    if constexpr (BF) return bfbits2f(((const unsigned short*)p)[i]);
    else              return ((const float*)p)[i];
}
template <bool BF>
__device__ __forceinline__ float4 ld4(const void* p, size_t i) {  // elems i..i+3
    if constexpr (BF) {
        const ushort4 s = *reinterpret_cast<const ushort4*>((const unsigned short*)p + i);
        return make_float4(bfbits2f(s.x), bfbits2f(s.y), bfbits2f(s.z), bfbits2f(s.w));
    } else {
        return *reinterpret_cast<const float4*>((const float*)p + i);
    }
}
template <bool BF>
__device__ __forceinline__ void st1(void* p, size_t i, float v) {
    if constexpr (BF) ((bf16*)p)[i] = __float2bfloat16(v);
    else              ((float*)p)[i] = v;
}

// ---------------------------------------------------------------------------
// Detector: classify float-tensor dtype from char_emb's first 256 ushorts.
// ---------------------------------------------------------------------------
__global__ void kdetect(const void* emb, u32* flag) {
    const int j = threadIdx.x;           // 64 lanes
    int s = 0;
    #pragma unroll
    for (int k = 0; k < 4; ++k) {
        const unsigned short u = ((const unsigned short*)emb)[j * 4 + k];
        const int e = (u >> 7) & 0xFF;
        s += (e >= 100 && e <= 133) ? 1 : 0;
    }
    #pragma unroll
    for (int off = 32; off >= 1; off >>= 1) s += __shfl_xor(s, off, 64);
    if (j == 0) *flag = (s >= 200) ? 1u : 0u;
}

// ---------------------------------------------------------------------------
// Kernel A: char LSTM. 8 words/block, 256 threads (thread j = gate row j).
// ---------------------------------------------------------------------------
template <bool BF>
__global__ __launch_bounds__(256, 2) void kchar(
        const u32* __restrict__ dtf,
        const int* __restrict__ char_idxs, const int* __restrict__ char_lens,
        const void* __restrict__ char_emb,
        const void* __restrict__ Wih, const void* __restrict__ Whh,
        const void* __restrict__ bih, const void* __restrict__ bhh,
        float* __restrict__ cfeat) {
    if ((*dtf != 0u) != BF) return;
    const int j = threadIdx.x;
    const int w0 = blockIdx.x * 8;

    __shared__ __align__(16) float emb_lds[128 * CE];     // 32 KB
    __shared__ __align__(16) float gates_lds[8 * 256];    // 8 KB
    __shared__ __align__(16) float h_lds[8 * CH];
    __shared__ __align__(16) float c_lds[8 * CH];
    __shared__ int cidx_lds[8 * LC];
    __shared__ int len_lds[8];

    {
        float4* emb4 = reinterpret_cast<float4*>(emb_lds);
        #pragma unroll
        for (int i = 0; i < 8; ++i) {
            const int c = i * 256 + j;
            emb4[c] = ld4<BF>(char_emb, (size_t)c * 4);
        }
    }
    if (j < 128) cidx_lds[j] = char_idxs[w0 * LC + j];
    if (j < 8)   len_lds[j]  = char_lens[w0 + j];
    h_lds[j] = 0.f; h_lds[j + 256] = 0.f;
    c_lds[j] = 0.f; c_lds[j + 256] = 0.f;

    float4 wih4[16], whh4[16];
    #pragma unroll
    for (int kc = 0; kc < 16; ++kc) {
        wih4[kc] = ld4<BF>(Wih, (size_t)j * CE + kc * 4);
        whh4[kc] = ld4<BF>(Whh, (size_t)j * CH + kc * 4);
    }
    const float bias = ld1<BF>(bih, j) + ld1<BF>(bhh, j);
    __syncthreads();

    for (int t = 0; t < LC; ++t) {
        for (int w = 0; w < 8; ++w) {
            const int ci = cidx_lds[w * LC + t];
            const float4* x4  = reinterpret_cast<const float4*>(emb_lds + ci * CE);
            const float4* hh4 = reinterpret_cast<const float4*>(h_lds + w * CH);
            float a0 = 0.f, a1 = 0.f, a2 = 0.f, a3 = 0.f;
            #pragma unroll
            for (int kc = 0; kc < 16; ++kc) {
                const float4 xv = x4[kc]; const float4 hv = hh4[kc];
                const float4 wi = wih4[kc]; const float4 wh = whh4[kc];
                a0 = fmaf(wi.x, xv.x, a0); a1 = fmaf(wi.y, xv.y, a1);
                a2 = fmaf(wi.z, xv.z, a2); a3 = fmaf(wi.w, xv.w, a3);
                a0 = fmaf(wh.x, hv.x, a0); a1 = fmaf(wh.y, hv.y, a1);
                a2 = fmaf(wh.z, hv.z, a2); a3 = fmaf(wh.w, hv.w, a3);
            }
            gates_lds[w * 256 + j] = bias + ((a0 + a1) + (a2 + a3));
        }
        __syncthreads();
        #pragma unroll
        for (int rep = 0; rep < 2; ++rep) {
            const int p = j + rep * 256;       // p = w*64 + u
            const int w = p >> 6, u = p & 63;
            const float ig = gates_lds[w * 256 + u];
            const float fg = gates_lds[w * 256 + 64 + u];
            const float gg = gates_lds[w * 256 + 128 + u];
            const float og = gates_lds[w * 256 + 192 + u];
            const float cn = sigm(fg) * c_lds[p] + sigm(ig) * tanh_fast(gg);
            const float hn = sigm(og) * tanh_fast(cn);
            c_lds[p] = cn; h_lds[p] = hn;
            if (t == len_lds[w] - 1)
                cfeat[(size_t)(w0 + w) * CH + u] = hn;
        }
        __syncthreads();
    }
}

// ---------------------------------------------------------------------------
// Kernel B: Gx ring chunk. 16 words/block.
// ---------------------------------------------------------------------------
template <bool BF>
__global__ __launch_bounds__(256) void kgx(
        const u32* __restrict__ dtf,
        int t0, const int* __restrict__ word_idxs, const float* __restrict__ cfeat,
        const void* __restrict__ wemb, const void* __restrict__ Wih,
        const void* __restrict__ bih, const void* __restrict__ bhh,
        float* __restrict__ Gxr) {
    if ((*dtf != 0u) != BF) return;
    const int j = threadIdx.x;
    const int wr0 = blockIdx.x * 16;       // ring row base
    const int w0g = t0 + wr0;              // global word base
    __shared__ __align__(16) float wx[16 * 192];
    __shared__ int widx[16];
    if (j < 16) widx[j] = word_idxs[w0g + j];
    __syncthreads();
    {
        const int w = j >> 4, ch = j & 15;
        const size_t eb = (size_t)widx[w] * WE + ch * 8;
        const float4 f0 = ld4<BF>(wemb, eb), f1 = ld4<BF>(wemb, eb + 4);
        float4* dst = reinterpret_cast<float4*>(wx + w * 192 + ch * 8);
        dst[0] = f0; dst[1] = f1;
        const float4 cf = *reinterpret_cast<const float4*>(
            cfeat + (size_t)(w0g + w) * CH + ch * 4);
        *reinterpret_cast<float4*>(wx + w * 192 + WE + ch * 4) = cf;
    }
    __syncthreads();

    for (int g = 0; g < 4; ++g) {
        const int r = g * 256 + j;
        float acc[16];
        #pragma unroll
        for (int w = 0; w < 16; ++w) acc[w] = 0.f;
        #pragma unroll 8
        for (int kc = 0; kc < 48; ++kc) {
            const float4 wv = ld4<BF>(Wih, (size_t)r * 192 + kc * 4);
            #pragma unroll
            for (int w = 0; w < 16; ++w) {
                const float4 xv = *reinterpret_cast<const float4*>(wx + w * 192 + kc * 4);
                acc[w] = fmaf(wv.x, xv.x, acc[w]);
                acc[w] = fmaf(wv.y, xv.y, acc[w]);
                acc[w] = fmaf(wv.z, xv.z, acc[w]);
                acc[w] = fmaf(wv.w, xv.w, acc[w]);
            }
        }
        const float bias = ld1<BF>(bih, r) + ld1<BF>(bhh, r);
        #pragma unroll
        for (int w = 0; w < 16; ++w)
            Gxr[(size_t)(wr0 + w) * 1024 + r] = acc[w] + bias;
    }
}

// ---------------------------------------------------------------------------
// Kernel C: word LSTM steps [t0, t1). Grid = 64 blocks x 512 threads; an
// election picks 4 worker blocks on ONE XCD (deadlock-free: all 64 blocks are
// co-resident and publish their XCC_ID unconditionally; decision is a pure
// function of the published array). Worker block b owns hidden units
// [64b, 64b+64). Split-K: thread j = (khalf=j>>8, r=j&255) holds Whh row
// ((r>>6)*256 + b*64 + (r&63)), columns [128*khalf, 128*khalf+128) in 128
// VGPRs -> no spill/remat. Cross-block h exchange via tagged u64 packets.
// ---------------------------------------------------------------------------
template <bool BF>
__global__ __launch_bounds__(512, 1) void kwlstm(
        const u32* __restrict__ dtf,
        int t0, int t1, const void* __restrict__ whh, const float* __restrict__ Gxr,
        float* __restrict__ hallr, u64* hgx2, float* csave, u32* xccpub) {
    if ((*dtf != 0u) != BF) return;
    const int j = threadIdx.x;

    __shared__ int role_s;
    // ---- same-XCD election ----
    if (j == 0) {
        const u32 xcc = __builtin_amdgcn_s_getreg(6164) & 0xFu;  // hwreg(XCC_ID,0,4)
        __hip_atomic_store(&xccpub[blockIdx.x], 0xE0000000u | xcc,
                           __ATOMIC_RELAXED, __HIP_MEMORY_SCOPE_AGENT);
    }
    if (j < 64) {
        u32 v;
        do {
            v = __hip_atomic_load(&xccpub[j], __ATOMIC_RELAXED,
                                  __HIP_MEMORY_SCOPE_AGENT);
        } while ((v >> 24) != 0xE0u);
        const u32 v0 = __shfl(v, 0, 64);
        const u64 mask = __ballot((v & 0xFu) == (v0 & 0xFu));
        const int myb = blockIdx.x;
        int role = -1;
        if (__popcll(mask) >= 4) {
            if ((mask >> myb) & 1ull) {
                const int rank = __popcll(mask & ((1ull << myb) - 1ull));
                if (rank < 4) role = rank;
            }
        } else {
            if (myb < 4) role = myb;   // fallback: cross-XCD, still correct
        }
        if (j == 0) role_s = role;
    }
    __syncthreads();
    const int b = role_s;
    if (b < 0) return;

    const int r  = j & 255;            // gate-row within block
    const int kh = j >> 8;             // K half
    const int R  = ((r >> 6) << 8) + b * 64 + (r & 63);   // global gate-row

    __shared__ __align__(16) float h_cur[256];
    __shared__ __align__(16) float part[512];
    __shared__ __align__(16) float gates[256];

    float4 wv[32];                      // 128 VGPRs, resident
    #pragma unroll
    for (int kc = 0; kc < 32; ++kc)
        wv[kc] = ld4<BF>(whh, (size_t)R * 256 + kh * 128 + kc * 4);

    if (j < 256) h_cur[j] = 0.f;
    float c_reg = 0.f;
    if (t0 > 0 && j < 64) c_reg = csave[b * 64 + j];

    float gx_cur = (j < 256) ? Gxr[(size_t)0 * 1024 + R] : 0.f;
    __syncthreads();

    for (int t = t0; t < t1; ++t) {
        if (t > 0 && j < 256) {
            u64 pk;
            do {
                pk = __hip_atomic_load(&hgx2[(size_t)(t & 1) * 256 + j],
                                       __ATOMIC_RELAXED, __HIP_MEMORY_SCOPE_AGENT);
            } while ((u32)(pk >> 32) != (u32)t);
            h_cur[j] = __uint_as_float((u32)pk);
        }
        __syncthreads();                               // A: h_cur ready
        float gx_next = 0.f;
        if (t + 1 < t1 && j < 256)                     // prefetch next Gx
            gx_next = Gxr[(size_t)(t + 1 - t0) * 1024 + R];
        float a0 = 0.f, a1 = 0.f, a2 = 0.f, a3 = 0.f;
        const float4* h4 = reinterpret_cast<const float4*>(h_cur) + kh * 32;
        #pragma unroll
        for (int kc = 0; kc < 32; ++kc) {
            const float4 hv = h4[kc];
            a0 = fmaf(wv[kc].x, hv.x, a0);
            a1 = fmaf(wv[kc].y, hv.y, a1);
            a2 = fmaf(wv[kc].z, hv.z, a2);
            a3 = fmaf(wv[kc].w, hv.w, a3);
        }
        part[j] = (a0 + a1) + (a2 + a3);
        __syncthreads();                               // B: partials ready
        if (j < 256) gates[j] = part[j] + part[j + 256] + gx_cur;
        __syncthreads();                               // C: gates ready
        if (j < 64) {
            const float ig = gates[j], fg = gates[64 + j];
            const float gg = gates[128 + j], og = gates[192 + j];
            const float cn = sigm(fg) * c_reg + sigm(ig) * tanh_fast(gg);
            c_reg = cn;
            const float hn = sigm(og) * tanh_fast(cn);
            hallr[(size_t)(t - t0) * 256 + b * 64 + j] = hn;
            const u64 pk = ((u64)(u32)(t + 1) << 32) | (u64)__float_as_uint(hn);
            __hip_atomic_store(&hgx2[(size_t)((t + 1) & 1) * 256 + b * 64 + j], pk,
                               __ATOMIC_RELAXED, __HIP_MEMORY_SCOPE_AGENT);
        }
        gx_cur = gx_next;
    }
    if (j < 64) csave[b * 64 + j] = c_reg;
}

// ---------------------------------------------------------------------------
// Kernel D: logits + log_softmax. One wave per word.
// ---------------------------------------------------------------------------
template <bool BF>
__global__ __launch_bounds__(64) void ktag(
        const u32* __restrict__ dtf,
        int t0, const float* __restrict__ hallr, const void* __restrict__ tagW,
        const void* __restrict__ tagb, void* __restrict__ out) {
    if ((*dtf != 0u) != BF) return;
    const int tr = blockIdx.x, j = threadIdx.x;
    const int t = t0 + tr;
    __shared__ __align__(16) float4 h4[64];
    h4[j] = reinterpret_cast<const float4*>(hallr + (size_t)tr * 256)[j];
    __syncthreads();
    float logit = -1e30f;
    if (j < NTAGS) {
        float a0 = 0.f, a1 = 0.f, a2 = 0.f, a3 = 0.f;
        #pragma unroll
        for (int kc = 0; kc < 64; ++kc) {
            const float4 wvv = ld4<BF>(tagW, (size_t)j * 256 + kc * 4);
            const float4 hv = h4[kc];
            a0 = fmaf(wvv.x, hv.x, a0); a1 = fmaf(wvv.y, hv.y, a1);
            a2 = fmaf(wvv.z, hv.z, a2); a3 = fmaf(wvv.w, hv.w, a3);
        }
        logit = ld1<BF>(tagb, j) + ((a0 + a1) + (a2 + a3));
    }
    float m = logit;
    #pragma unroll
    for (int off = 32; off >= 1; off >>= 1) m = fmaxf(m, __shfl_xor(m, off, 64));
    const float e = (j < NTAGS) ? __expf(logit - m) : 0.f;
    float ssum = e;
    #pragma unroll
    for (int off = 32; off >= 1; off >>= 1) ssum += __shfl_xor(ssum, off, 64);
    if (j < NTAGS)
        st1<BF>(out, (size_t)t * NTAGS + j, logit - m - __logf(ssum));
}

// ---------------------------------------------------------------------------
extern "C" void kernel_launch(void* const* d_in, const int* in_sizes, int n_in,
                              void* d_out, int out_size, void* d_ws, size_t ws_size,
                              hipStream_t stream) {
    const int*  word_idxs = (const int*)d_in[0];
    const int*  char_idxs = (const int*)d_in[1];
    const int*  char_lens = (const int*)d_in[2];
    const void* char_emb  = d_in[3];
    const void* char_Wih  = d_in[4];
    const void* char_Whh  = d_in[5];
    const void* char_bih  = d_in[6];
    const void* char_bhh  = d_in[7];
    const void* word_emb  = d_in[8];
    const void* word_Wih  = d_in[9];
    const void* word_Whh  = d_in[10];
    const void* word_bih  = d_in[11];
    const void* word_bhh  = d_in[12];
    const void* tag_W     = d_in[13];
    const void* tag_b     = d_in[14];

    // ws layout:
    //   [0,64)        dtflag u32
    //   [64,4160)     hgx2 u64[2][256]
    //   [4224,5248)   csave f32[256]
    //   [5248,5504)   xccpub u32[64]
    //   [8192,+2MB)   cfeat f32[8192*64]
    //   [ring0,...)   Gx ring f32[CT*1024] + hall ring f32[CT*256]
    char* ws = (char*)d_ws;
    u32*   dtf    = (u32*)(ws);
    u64*   hgx2   = (u64*)(ws + 64);
    float* csave  = (float*)(ws + 4224);
    u32*   xccpub = (u32*)(ws + 5248);
    float* cfeat  = (float*)(ws + 8192);
    const size_t ring0 = 8192 + (size_t)S_LEN * CH * 4;

    int NC = 256;
    const int ncs[9] = {1, 2, 4, 8, 16, 32, 64, 128, 256};
    for (int i = 0; i < 9; ++i) {
        const int ct = S_LEN / ncs[i];
        if (ring0 + (size_t)ct * 5120 <= ws_size) { NC = ncs[i]; break; }
    }
    const int CT = S_LEN / NC;
    float* Gxr   = (float*)(ws + ring0);
    float* hallr = (float*)(ws + ring0 + (size_t)CT * 4096);

    hipLaunchKernelGGL(kdetect, dim3(1), dim3(64), 0, stream, char_emb, dtf);
    hipLaunchKernelGGL(kchar<true>,  dim3(S_LEN / 8), dim3(256), 0, stream,
                       dtf, char_idxs, char_lens, char_emb, char_Wih, char_Whh,
                       char_bih, char_bhh, cfeat);
    hipLaunchKernelGGL(kchar<false>, dim3(S_LEN / 8), dim3(256), 0, stream,
                       dtf, char_idxs, char_lens, char_emb, char_Wih, char_Whh,
                       char_bih, char_bhh, cfeat);
    for (int c = 0; c < NC; ++c) {
        const int t0 = c * CT;
        hipLaunchKernelGGL(kgx<true>,  dim3(CT / 16), dim3(256), 0, stream,
                           dtf, t0, word_idxs, cfeat, word_emb, word_Wih,
                           word_bih, word_bhh, Gxr);
        hipLaunchKernelGGL(kgx<false>, dim3(CT / 16), dim3(256), 0, stream,
                           dtf, t0, word_idxs, cfeat, word_emb, word_Wih,
                           word_bih, word_bhh, Gxr);
        hipLaunchKernelGGL(kwlstm<true>,  dim3(64), dim3(512), 0, stream,
                           dtf, t0, t0 + CT, word_Whh, Gxr, hallr, hgx2, csave, xccpub);
        hipLaunchKernelGGL(kwlstm<false>, dim3(64), dim3(512), 0, stream,
                           dtf, t0, t0 + CT, word_Whh, Gxr, hallr, hgx2, csave, xccpub);
        hipLaunchKernelGGL(ktag<true>,  dim3(CT), dim3(64), 0, stream,
                           dtf, t0, hallr, tag_W, tag_b, d_out);
        hipLaunchKernelGGL(ktag<false>, dim3(CT), dim3(64), 0, stream,
                           dtf, t0, hallr, tag_W, tag_b, d_out);
    }
}

// Round 5
// 12180.526 us; speedup vs baseline: 1.6961x; 1.0431x over previous
//
#include <hip/hip_runtime.h>
#include <hip/hip_bf16.h>

#define S_LEN 8192
#define LC 16
#define CE 64
#define CH 64
#define WE 128
#define NTAGS 50

using bf16 = __hip_bfloat16;
typedef unsigned int u32;
typedef unsigned long long u64;

__device__ __forceinline__ float bfbits2f(unsigned short u) {
    union { unsigned int i; float f; } v; v.i = ((unsigned int)u) << 16; return v.f;
}
__device__ __forceinline__ float sigm(float x) {
    return __builtin_amdgcn_rcpf(1.0f + __expf(-x));
}
__device__ __forceinline__ float tanh_fast(float x) {
    return 1.0f - 2.0f * __builtin_amdgcn_rcpf(__expf(2.0f * x) + 1.0f);
}

// dtype-generic accessors ----------------------------------------------------
template <bool BF>
__device__ __forceinline__ float ld1(const void* p, size_t i) {
    if constexpr (BF) return bfbits2f(((const unsigned short*)p)[i]);
    else              return ((const float*)p)[i];
}
template <bool BF>
__device__ __forceinline__ float4 ld4(const void* p, size_t i) {  // elems i..i+3
    if constexpr (BF) {
        const ushort4 s = *reinterpret_cast<const ushort4*>((const unsigned short*)p + i);
        return make_float4(bfbits2f(s.x), bfbits2f(s.y), bfbits2f(s.z), bfbits2f(s.w));
    } else {
        return *reinterpret_cast<const float4*>((const float*)p + i);
    }
}
template <bool BF>
__device__ __forceinline__ void st1(void* p, size_t i, float v) {
    if constexpr (BF) ((bf16*)p)[i] = __float2bfloat16(v);
    else              ((float*)p)[i] = v;
}

// ---------------------------------------------------------------------------
// Detector: classify float-tensor dtype from char_emb's first 256 ushorts.
// ---------------------------------------------------------------------------
__global__ void kdetect(const void* emb, u32* flag) {
    const int j = threadIdx.x;           // 64 lanes
    int s = 0;
    #pragma unroll
    for (int k = 0; k < 4; ++k) {
        const unsigned short u = ((const unsigned short*)emb)[j * 4 + k];
        const int e = (u >> 7) & 0xFF;
        s += (e >= 100 && e <= 133) ? 1 : 0;
    }
    #pragma unroll
    for (int off = 32; off >= 1; off >>= 1) s += __shfl_xor(s, off, 64);
    if (j == 0) *flag = (s >= 200) ? 1u : 0u;
}

// ---------------------------------------------------------------------------
// Kernel A: char LSTM. 8 words/block, 256 threads (thread j = gate row j).
// ---------------------------------------------------------------------------
template <bool BF>
__global__ __launch_bounds__(256, 2) void kchar(
        const u32* __restrict__ dtf,
        const int* __restrict__ char_idxs, const int* __restrict__ char_lens,
        const void* __restrict__ char_emb,
        const void* __restrict__ Wih, const void* __restrict__ Whh,
        const void* __restrict__ bih, const void* __restrict__ bhh,
        float* __restrict__ cfeat) {
    if ((*dtf != 0u) != BF) return;
    const int j = threadIdx.x;
    const int w0 = blockIdx.x * 8;

    __shared__ __align__(16) float emb_lds[128 * CE];     // 32 KB
    __shared__ __align__(16) float gates_lds[8 * 256];    // 8 KB
    __shared__ __align__(16) float h_lds[8 * CH];
    __shared__ __align__(16) float c_lds[8 * CH];
    __shared__ int cidx_lds[8 * LC];
    __shared__ int len_lds[8];

    {
        float4* emb4 = reinterpret_cast<float4*>(emb_lds);
        #pragma unroll
        for (int i = 0; i < 8; ++i) {
            const int c = i * 256 + j;
            emb4[c] = ld4<BF>(char_emb, (size_t)c * 4);
        }
    }
    if (j < 128) cidx_lds[j] = char_idxs[w0 * LC + j];
    if (j < 8)   len_lds[j]  = char_lens[w0 + j];
    h_lds[j] = 0.f; h_lds[j + 256] = 0.f;
    c_lds[j] = 0.f; c_lds[j + 256] = 0.f;

    float4 wih4[16], whh4[16];
    #pragma unroll
    for (int kc = 0; kc < 16; ++kc) {
        wih4[kc] = ld4<BF>(Wih, (size_t)j * CE + kc * 4);
        whh4[kc] = ld4<BF>(Whh, (size_t)j * CH + kc * 4);
    }
    const float bias = ld1<BF>(bih, j) + ld1<BF>(bhh, j);
    __syncthreads();

    for (int t = 0; t < LC; ++t) {
        for (int w = 0; w < 8; ++w) {
            const int ci = cidx_lds[w * LC + t];
            const float4* x4  = reinterpret_cast<const float4*>(emb_lds + ci * CE);
            const float4* hh4 = reinterpret_cast<const float4*>(h_lds + w * CH);
            float a0 = 0.f, a1 = 0.f, a2 = 0.f, a3 = 0.f;
            #pragma unroll
            for (int kc = 0; kc < 16; ++kc) {
                const float4 xv = x4[kc]; const float4 hv = hh4[kc];
                const float4 wi = wih4[kc]; const float4 wh = whh4[kc];
                a0 = fmaf(wi.x, xv.x, a0); a1 = fmaf(wi.y, xv.y, a1);
                a2 = fmaf(wi.z, xv.z, a2); a3 = fmaf(wi.w, xv.w, a3);
                a0 = fmaf(wh.x, hv.x, a0); a1 = fmaf(wh.y, hv.y, a1);
                a2 = fmaf(wh.z, hv.z, a2); a3 = fmaf(wh.w, hv.w, a3);
            }
            gates_lds[w * 256 + j] = bias + ((a0 + a1) + (a2 + a3));
        }
        __syncthreads();
        #pragma unroll
        for (int rep = 0; rep < 2; ++rep) {
            const int p = j + rep * 256;       // p = w*64 + u
            const int w = p >> 6, u = p & 63;
            const float ig = gates_lds[w * 256 + u];
            const float fg = gates_lds[w * 256 + 64 + u];
            const float gg = gates_lds[w * 256 + 128 + u];
            const float og = gates_lds[w * 256 + 192 + u];
            const float cn = sigm(fg) * c_lds[p] + sigm(ig) * tanh_fast(gg);
            const float hn = sigm(og) * tanh_fast(cn);
            c_lds[p] = cn; h_lds[p] = hn;
            if (t == len_lds[w] - 1)
                cfeat[(size_t)(w0 + w) * CH + u] = hn;
        }
        __syncthreads();
    }
}

// ---------------------------------------------------------------------------
// Kernel B: Gx ring chunk. 16 words/block.
// ---------------------------------------------------------------------------
template <bool BF>
__global__ __launch_bounds__(256) void kgx(
        const u32* __restrict__ dtf,
        int t0, const int* __restrict__ word_idxs, const float* __restrict__ cfeat,
        const void* __restrict__ wemb, const void* __restrict__ Wih,
        const void* __restrict__ bih, const void* __restrict__ bhh,
        float* __restrict__ Gxr) {
    if ((*dtf != 0u) != BF) return;
    const int j = threadIdx.x;
    const int wr0 = blockIdx.x * 16;       // ring row base
    const int w0g = t0 + wr0;              // global word base
    __shared__ __align__(16) float wx[16 * 192];
    __shared__ int widx[16];
    if (j < 16) widx[j] = word_idxs[w0g + j];
    __syncthreads();
    {
        const int w = j >> 4, ch = j & 15;
        const size_t eb = (size_t)widx[w] * WE + ch * 8;
        const float4 f0 = ld4<BF>(wemb, eb), f1 = ld4<BF>(wemb, eb + 4);
        float4* dst = reinterpret_cast<float4*>(wx + w * 192 + ch * 8);
        dst[0] = f0; dst[1] = f1;
        const float4 cf = *reinterpret_cast<const float4*>(
            cfeat + (size_t)(w0g + w) * CH + ch * 4);
        *reinterpret_cast<float4*>(wx + w * 192 + WE + ch * 4) = cf;
    }
    __syncthreads();

    for (int g = 0; g < 4; ++g) {
        const int r = g * 256 + j;
        float acc[16];
        #pragma unroll
        for (int w = 0; w < 16; ++w) acc[w] = 0.f;
        #pragma unroll 8
        for (int kc = 0; kc < 48; ++kc) {
            const float4 wv = ld4<BF>(Wih, (size_t)r * 192 + kc * 4);
            #pragma unroll
            for (int w = 0; w < 16; ++w) {
                const float4 xv = *reinterpret_cast<const float4*>(wx + w * 192 + kc * 4);
                acc[w] = fmaf(wv.x, xv.x, acc[w]);
                acc[w] = fmaf(wv.y, xv.y, acc[w]);
                acc[w] = fmaf(wv.z, xv.z, acc[w]);
                acc[w] = fmaf(wv.w, xv.w, acc[w]);
            }
        }
        const float bias = ld1<BF>(bih, r) + ld1<BF>(bhh, r);
        #pragma unroll
        for (int w = 0; w < 16; ++w)
            Gxr[(size_t)(wr0 + w) * 1024 + r] = acc[w] + bias;
    }
}

// ---------------------------------------------------------------------------
// Kernel C: word LSTM steps [t0, t1). Grid = 64 blocks x 1024 threads; election
// picks 4 worker blocks on ONE XCD (epoch-tagged publishes so stale values from
// a previous chunk can't be mistaken; role assignment is a pure function of the
// published array -> always exactly 4 distinct workers, deadlock-free).
// Worker block b owns hidden units [64b,64b+64). Split-K=4: thread j =
// (kq=j>>8, r=j&255) holds Whh row ((r>>6)*256+b*64+(r&63)) cols [64kq,64kq+64)
// in 16 float4 = 64 VGPRs (fits the 128-reg budget at 16 waves/CU -> no AGPR
// spill). Per step: gather remote h (192 lanes spin on tagged u64 packets) ->
// barrier -> quarter-row matvec (+gx folded into kq==0 partials) -> barrier ->
// lanes j<64 sum 16 partials, gate math, publish packet + own h to LDS.
// ---------------------------------------------------------------------------
template <bool BF>
__global__ __launch_bounds__(1024, 4) void kwlstm(
        const u32* __restrict__ dtf,
        int t0, int t1, int epoch, const void* __restrict__ whh,
        const float* __restrict__ Gxr,
        float* __restrict__ hallr, u64* hgx2, float* csave, u32* xccpub) {
    if ((*dtf != 0u) != BF) return;
    const int j = threadIdx.x;

    __shared__ int role_s;
    // ---- same-XCD election (epoch-tagged) ----
    const u32 etag = 0xB0u + ((u32)epoch & 0xFu);
    if (j == 0) {
        const u32 xcc = __builtin_amdgcn_s_getreg(6164) & 0xFu;  // hwreg(XCC_ID,0,4)
        __hip_atomic_store(&xccpub[blockIdx.x], (etag << 24) | xcc,
                           __ATOMIC_RELAXED, __HIP_MEMORY_SCOPE_AGENT);
    }
    if (j < 64) {
        u32 v;
        do {
            v = __hip_atomic_load(&xccpub[j], __ATOMIC_RELAXED,
                                  __HIP_MEMORY_SCOPE_AGENT);
        } while ((v >> 24) != etag);
        const u32 v0 = __shfl(v, 0, 64);
        const u64 mask = __ballot((v & 0xFu) == (v0 & 0xFu));
        const int myb = blockIdx.x;
        int role = -1;
        if (__popcll(mask) >= 4) {
            if ((mask >> myb) & 1ull) {
                const int rank = __popcll(mask & ((1ull << myb) - 1ull));
                if (rank < 4) role = rank;
            }
        } else {
            if (myb < 4) role = myb;   // fallback: cross-XCD, still correct
        }
        if (j == 0) role_s = role;
    }
    __syncthreads();
    const int b = role_s;
    if (b < 0) return;

    const int r  = j & 255;            // gate-row within block (g*64+u)
    const int kq = j >> 8;             // K quarter 0..3
    const int R  = ((r >> 6) << 8) + b * 64 + (r & 63);   // global gate-row

    __shared__ __align__(16) float h_cur[256];
    __shared__ __align__(16) float part[1024];

    float4 wv[16];                      // 64 VGPRs, resident
    #pragma unroll
    for (int kc = 0; kc < 16; ++kc)
        wv[kc] = ld4<BF>(whh, (size_t)R * 256 + kq * 64 + kc * 4);

    if (j < 256) h_cur[j] = 0.f;
    float c_reg = 0.f;
    if (t0 > 0 && j < 64) c_reg = csave[b * 64 + j];

    // 2-deep Gx pipeline (held by kq==0 threads, i.e. j<256)
    float gxA = (j < 256) ? Gxr[(size_t)0 * 1024 + R] : 0.f;              // t0
    float gxB = (j < 256 && t0 + 1 < t1) ? Gxr[(size_t)1 * 1024 + R] : 0.f;
    __syncthreads();

    for (int t = t0; t < t1; ++t) {
        if (t > 0) {
            if (t == t0) {                      // chunk start: gather all 256
                if (j < 256) {
                    u64 pk;
                    do {
                        pk = __hip_atomic_load(&hgx2[(size_t)(t & 1) * 256 + j],
                                               __ATOMIC_RELAXED, __HIP_MEMORY_SCOPE_AGENT);
                    } while ((u32)(pk >> 32) != (u32)t);
                    h_cur[j] = __uint_as_float((u32)pk);
                }
            } else {                            // steady state: 192 remote only
                if (j < 192) {
                    const int gu = j + (j >= b * 64 ? 64 : 0);
                    u64 pk;
                    do {
                        pk = __hip_atomic_load(&hgx2[(size_t)(t & 1) * 256 + gu],
                                               __ATOMIC_RELAXED, __HIP_MEMORY_SCOPE_AGENT);
                    } while ((u32)(pk >> 32) != (u32)t);
                    h_cur[gu] = __uint_as_float((u32)pk);
                }
            }
        }
        __syncthreads();                               // A: h_cur ready
        float gxN = 0.f;                               // prefetch Gx[t+2]
        if (j < 256 && t + 2 < t1)
            gxN = Gxr[(size_t)(t + 2 - t0) * 1024 + R];
        float a0 = 0.f, a1 = 0.f, a2 = 0.f, a3 = 0.f;
        const float4* h4 = reinterpret_cast<const float4*>(h_cur) + kq * 16;
        #pragma unroll
        for (int kc = 0; kc < 16; ++kc) {
            const float4 hv = h4[kc];
            a0 = fmaf(wv[kc].x, hv.x, a0);
            a1 = fmaf(wv[kc].y, hv.y, a1);
            a2 = fmaf(wv[kc].z, hv.z, a2);
            a3 = fmaf(wv[kc].w, hv.w, a3);
        }
        part[j] = ((a0 + a1) + (a2 + a3)) + (kq == 0 ? gxA : 0.f);
        __syncthreads();                               // B: partials ready
        if (j < 64) {
            const float ig = part[j]       + part[j + 256] + part[j + 512] + part[j + 768];
            const float fg = part[j + 64]  + part[j + 320] + part[j + 576] + part[j + 832];
            const float gg = part[j + 128] + part[j + 384] + part[j + 640] + part[j + 896];
            const float og = part[j + 192] + part[j + 448] + part[j + 704] + part[j + 960];
            const float cn = sigm(fg) * c_reg + sigm(ig) * tanh_fast(gg);
            c_reg = cn;
            const float hn = sigm(og) * tanh_fast(cn);
            const u64 pk = ((u64)(u32)(t + 1) << 32) | (u64)__float_as_uint(hn);
            __hip_atomic_store(&hgx2[(size_t)((t + 1) & 1) * 256 + b * 64 + j], pk,
                               __ATOMIC_RELAXED, __HIP_MEMORY_SCOPE_AGENT);
            h_cur[b * 64 + j] = hn;     // own slice local; barrier A orders it
            hallr[(size_t)(t - t0) * 256 + b * 64 + j] = hn;
        }
        gxA = gxB; gxB = gxN;
    }
    if (j < 64) csave[b * 64 + j] = c_reg;
}

// ---------------------------------------------------------------------------
// Kernel D: logits + log_softmax. One wave per word.
// ---------------------------------------------------------------------------
template <bool BF>
__global__ __launch_bounds__(64) void ktag(
        const u32* __restrict__ dtf,
        int t0, const float* __restrict__ hallr, const void* __restrict__ tagW,
        const void* __restrict__ tagb, void* __restrict__ out) {
    if ((*dtf != 0u) != BF) return;
    const int tr = blockIdx.x, j = threadIdx.x;
    const int t = t0 + tr;
    __shared__ __align__(16) float4 h4[64];
    h4[j] = reinterpret_cast<const float4*>(hallr + (size_t)tr * 256)[j];
    __syncthreads();
    float logit = -1e30f;
    if (j < NTAGS) {
        float a0 = 0.f, a1 = 0.f, a2 = 0.f, a3 = 0.f;
        #pragma unroll
        for (int kc = 0; kc < 64; ++kc) {
            const float4 wvv = ld4<BF>(tagW, (size_t)j * 256 + kc * 4);
            const float4 hv = h4[kc];
            a0 = fmaf(wvv.x, hv.x, a0); a1 = fmaf(wvv.y, hv.y, a1);
            a2 = fmaf(wvv.z, hv.z, a2); a3 = fmaf(wvv.w, hv.w, a3);
        }
        logit = ld1<BF>(tagb, j) + ((a0 + a1) + (a2 + a3));
    }
    float m = logit;
    #pragma unroll
    for (int off = 32; off >= 1; off >>= 1) m = fmaxf(m, __shfl_xor(m, off, 64));
    const float e = (j < NTAGS) ? __expf(logit - m) : 0.f;
    float ssum = e;
    #pragma unroll
    for (int off = 32; off >= 1; off >>= 1) ssum += __shfl_xor(ssum, off, 64);
    if (j < NTAGS)
        st1<BF>(out, (size_t)t * NTAGS + j, logit - m - __logf(ssum));
}

// ---------------------------------------------------------------------------
extern "C" void kernel_launch(void* const* d_in, const int* in_sizes, int n_in,
                              void* d_out, int out_size, void* d_ws, size_t ws_size,
                              hipStream_t stream) {
    const int*  word_idxs = (const int*)d_in[0];
    const int*  char_idxs = (const int*)d_in[1];
    const int*  char_lens = (const int*)d_in[2];
    const void* char_emb  = d_in[3];
    const void* char_Wih  = d_in[4];
    const void* char_Whh  = d_in[5];
    const void* char_bih  = d_in[6];
    const void* char_bhh  = d_in[7];
    const void* word_emb  = d_in[8];
    const void* word_Wih  = d_in[9];
    const void* word_Whh  = d_in[10];
    const void* word_bih  = d_in[11];
    const void* word_bhh  = d_in[12];
    const void* tag_W     = d_in[13];
    const void* tag_b     = d_in[14];

    // ws layout:
    //   [0,64)        dtflag u32
    //   [64,4160)     hgx2 u64[2][256]
    //   [4224,5248)   csave f32[256]
    //   [5248,5504)   xccpub u32[64]
    //   [8192,+2MB)   cfeat f32[8192*64]
    //   [ring0,...)   Gx ring f32[CT*1024] + hall ring f32[CT*256]
    char* ws = (char*)d_ws;
    u32*   dtf    = (u32*)(ws);
    u64*   hgx2   = (u64*)(ws + 64);
    float* csave  = (float*)(ws + 4224);
    u32*   xccpub = (u32*)(ws + 5248);
    float* cfeat  = (float*)(ws + 8192);
    const size_t ring0 = 8192 + (size_t)S_LEN * CH * 4;

    int NC = 256;
    const int ncs[9] = {1, 2, 4, 8, 16, 32, 64, 128, 256};
    for (int i = 0; i < 9; ++i) {
        const int ct = S_LEN / ncs[i];
        if (ring0 + (size_t)ct * 5120 <= ws_size) { NC = ncs[i]; break; }
    }
    const int CT = S_LEN / NC;
    float* Gxr   = (float*)(ws + ring0);
    float* hallr = (float*)(ws + ring0 + (size_t)CT * 4096);

    hipLaunchKernelGGL(kdetect, dim3(1), dim3(64), 0, stream, char_emb, dtf);
    hipLaunchKernelGGL(kchar<true>,  dim3(S_LEN / 8), dim3(256), 0, stream,
                       dtf, char_idxs, char_lens, char_emb, char_Wih, char_Whh,
                       char_bih, char_bhh, cfeat);
    hipLaunchKernelGGL(kchar<false>, dim3(S_LEN / 8), dim3(256), 0, stream,
                       dtf, char_idxs, char_lens, char_emb, char_Wih, char_Whh,
                       char_bih, char_bhh, cfeat);
    for (int c = 0; c < NC; ++c) {
        const int t0 = c * CT;
        hipLaunchKernelGGL(kgx<true>,  dim3(CT / 16), dim3(256), 0, stream,
                           dtf, t0, word_idxs, cfeat, word_emb, word_Wih,
                           word_bih, word_bhh, Gxr);
        hipLaunchKernelGGL(kgx<false>, dim3(CT / 16), dim3(256), 0, stream,
                           dtf, t0, word_idxs, cfeat, word_emb, word_Wih,
                           word_bih, word_bhh, Gxr);
        hipLaunchKernelGGL(kwlstm<true>,  dim3(64), dim3(1024), 0, stream,
                           dtf, t0, t0 + CT, c, word_Whh, Gxr, hallr, hgx2, csave, xccpub);
        hipLaunchKernelGGL(kwlstm<false>, dim3(64), dim3(1024), 0, stream,
                           dtf, t0, t0 + CT, c, word_Whh, Gxr, hallr, hgx2, csave, xccpub);
        hipLaunchKernelGGL(ktag<true>,  dim3(CT), dim3(64), 0, stream,
                           dtf, t0, hallr, tag_W, tag_b, d_out);
        hipLaunchKernelGGL(ktag<false>, dim3(CT), dim3(64), 0, stream,
                           dtf, t0, hallr, tag_W, tag_b, d_out);
    }
}